// Round 20
// baseline (843.468 us; speedup 1.0000x reference)
//
#include <hip/hip_runtime.h>

#define NB 1024   // batch
#define TT 32     // encoder length
#define DIN 256   // input dim
#define HD 256    // hidden dim
#define NC 38     // classes
#define NSTEP 26  // decode steps

typedef unsigned short ushort_t;
typedef __attribute__((ext_vector_type(8))) short bf16x8;
typedef __attribute__((ext_vector_type(8))) unsigned short us8;
typedef __attribute__((ext_vector_type(4))) float f32x4;

#define GLOAD_LDS16(g, l) \
  __builtin_amdgcn_global_load_lds((const __attribute__((address_space(1))) unsigned int*)(g), \
                                   (__attribute__((address_space(3))) unsigned int*)(l), 16, 0, 0)

__device__ __forceinline__ unsigned short f2bf(float x) {
    union { float f; unsigned u; } v; v.f = x;
    unsigned r = v.u + 0x7fff + ((v.u >> 16) & 1);   // RNE
    return (unsigned short)(r >> 16);
}
__device__ __forceinline__ float bf2f(unsigned short h) {
    union { unsigned u; float f; } v; v.u = ((unsigned)h) << 16;
    return v.f;
}
__device__ __forceinline__ float fast_tanh(float x) {
    float xc = fminf(fmaxf(x, -15.f), 15.f);
    float z = __expf(2.f * xc);
    return (z - 1.f) * __builtin_amdgcn_rcpf(z + 1.f);
}
__device__ __forceinline__ float fast_sig(float x) {
    return __builtin_amdgcn_rcpf(1.f + __expf(-x));
}

// ---------------------------------------------------------------------------
// prep_all: 3904 blocks.  (verbatim, proven)
// ---------------------------------------------------------------------------
__global__ __launch_bounds__(256) void prep_all(
    const float* __restrict__ w_ih, const float* __restrict__ w_hh,
    const float* __restrict__ w_i2h, const float* __restrict__ w_h2h,
    const float* __restrict__ enc, const float* __restrict__ w_gen,
    ushort_t* __restrict__ B2g, ushort_t* __restrict__ B2i,
    ushort_t* __restrict__ w2hb, ushort_t* __restrict__ encA2,
    ushort_t* __restrict__ encb, ushort_t* __restrict__ w_genP,
    float* __restrict__ zbase)
{
    const int bid = blockIdx.x, tid = threadIdx.x;
    if (bid < 1024) {
        int j = bid;
        int jorig = ((j & 3) << 8) + (j >> 2);   // gate-interleaved cols
        for (int k = tid; k < 512; k += 256) {
            float x = (k < 256) ? w_ih[(size_t)jorig * 294 + k]
                                : w_hh[(size_t)jorig * 256 + (k - 256)];
            unsigned short hi = f2bf(x);
            unsigned short lo = f2bf(x - bf2f(hi));
            size_t r = (size_t)j * 1536;
            B2g[r + k] = hi; B2g[r + 512 + k] = lo; B2g[r + 1024 + k] = hi;
        }
    } else if (bid < 1280) {
        int n = bid - 1024;
        float x = w_i2h[(size_t)n * 256 + tid];
        unsigned short hi = f2bf(x);
        unsigned short lo = f2bf(x - bf2f(hi));
        size_t r = (size_t)n * 768;
        B2i[r + tid] = hi; B2i[r + 256 + tid] = lo; B2i[r + 512 + tid] = hi;
    } else if (bid < 1536) {
        int j = bid - 1280;
        w2hb[(size_t)j * 256 + tid] = f2bf(w_h2h[(size_t)j * 256 + tid]);
    } else if (bid < 3584) {
        int base = (bid - 1536) * 16;
#pragma unroll
        for (int rr = 0; rr < 16; rr++) {
            size_t row = base + rr;
            float x = enc[row * 256 + tid];
            unsigned short hi = f2bf(x);
            unsigned short lo = f2bf(x - bf2f(hi));
            encA2[row * 512 + tid] = hi;
            encA2[row * 512 + 256 + tid] = lo;
            encb[row * 256 + tid] = hi;
        }
    } else if (bid < 3648) {
        int j = bid - 3584;
        float x = (j < NC) ? w_gen[(size_t)j * 256 + tid] : 0.f;
        unsigned short hi = f2bf(x);
        unsigned short lo = f2bf(x - bf2f(hi));
        size_t r = (size_t)j * 768;
        w_genP[r + tid] = hi; w_genP[r + 256 + tid] = lo; w_genP[r + 512 + tid] = hi;
    } else {
        float* z = zbase + (size_t)(bid - 3648) * 4096;
        const float4 f4z = make_float4(0.f, 0.f, 0.f, 0.f);
#pragma unroll
        for (int k = 0; k < 4; k++)
            *(float4*)&z[(tid + k * 256) * 4] = f4z;
    }
}

// ---------------------------------------------------------------------------
// hproj_pipe: Hb[m][n] = bf16( sum_k enc[m][k]*w_i2h[n][k] )   (proven)
// ---------------------------------------------------------------------------
__global__ __launch_bounds__(256) void hproj_pipe(
    const ushort_t* __restrict__ encA2, const ushort_t* __restrict__ B2i,
    ushort_t* __restrict__ Hb)
{
    __shared__ ushort_t lA[2][64 * 128];
    __shared__ ushort_t lB[2][64 * 128];

    const int tid = threadIdx.x;
    const int lane = tid & 63, wid = tid >> 6;
    const int wm = wid >> 1, wn = wid & 1;
    const int m0 = blockIdx.x * 64, n0 = blockIdx.y * 64;

    f32x4 acc[2][2];
    const f32x4 fz = {0.f, 0.f, 0.f, 0.f};
    acc[0][0] = fz; acc[0][1] = fz; acc[1][0] = fz; acc[1][1] = fz;

    auto stage = [&](int t, int buf) {
#pragma unroll
        for (int i = 0; i < 4; i++) {
            int cpos = tid + i * 256;
            int m = cpos >> 4, p = cpos & 15;
            int g = p ^ (m & 7);
            int vk = t * 128 + g * 8;
            int acol = (vk < 256) ? vk : vk - 256;
            GLOAD_LDS16(&encA2[(size_t)(m0 + m) * 512 + acol], &lA[buf][cpos * 8]);
        }
#pragma unroll
        for (int i = 0; i < 4; i++) {
            int cpos = tid + i * 256;
            int n = cpos >> 4, p = cpos & 15;
            int g = p ^ (n & 7);
            GLOAD_LDS16(&B2i[(size_t)(n0 + n) * 768 + t * 128 + g * 8], &lB[buf][cpos * 8]);
        }
    };

    stage(0, 0);
    stage(1, 1);

    for (int t = 0; t < 6; t++) {
        int cur = t & 1;
        if (t < 5) asm volatile("s_waitcnt vmcnt(8)" ::: "memory");
        else       asm volatile("s_waitcnt vmcnt(0)" ::: "memory");
        __syncthreads();
#pragma unroll
        for (int kk = 0; kk < 4; kk++) {
            int g = kk * 4 + (lane >> 4);
            bf16x8 af[2], bfr[2];
#pragma unroll
            for (int mi = 0; mi < 2; mi++) {
                int m = wm * 32 + mi * 16 + (lane & 15);
                af[mi] = *(const bf16x8*)&lA[cur][m * 128 + ((g ^ (m & 7)) << 3)];
            }
#pragma unroll
            for (int ni = 0; ni < 2; ni++) {
                int n = wn * 32 + ni * 16 + (lane & 15);
                bfr[ni] = *(const bf16x8*)&lB[cur][n * 128 + ((g ^ (n & 7)) << 3)];
            }
#pragma unroll
            for (int mi = 0; mi < 2; mi++)
#pragma unroll
                for (int ni = 0; ni < 2; ni++)
                    acc[mi][ni] = __builtin_amdgcn_mfma_f32_16x16x32_bf16(af[mi], bfr[ni], acc[mi][ni], 0, 0, 0);
        }
        __syncthreads();
        if (t + 2 < 6) stage(t + 2, cur);
    }

    const int r4 = (lane >> 4) * 4;
#pragma unroll
    for (int mi = 0; mi < 2; mi++)
#pragma unroll
        for (int r = 0; r < 4; r++) {
            size_t row = m0 + wm * 32 + mi * 16 + r4 + r;
#pragma unroll
            for (int ni = 0; ni < 2; ni++) {
                int col = n0 + wn * 32 + ni * 16 + (lane & 15);
                Hb[row * 256 + col] = f2bf(acc[mi][ni][r]);
            }
        }
}

// ---------------------------------------------------------------------------
// gates_lstm: gates GEMM + fused LSTM epilogue.  BM=32, 512 blocks (2/CU).
// (verbatim round 18/19, proven)
// ---------------------------------------------------------------------------
__global__ __launch_bounds__(256) void gates_lstm(
    const ushort_t* __restrict__ A2in, const ushort_t* __restrict__ B2,
    const float* __restrict__ b_ih, const float* __restrict__ b_hh,
    const float* __restrict__ w_ih, const int* __restrict__ text,
    float* __restrict__ c, float* __restrict__ h,
    ushort_t* __restrict__ A2out, ushort_t* __restrict__ hseq2,
    int step)
{
    __shared__ ushort_t lA[2][32 * 128];   // 8 KB x2
    __shared__ ushort_t lB[2][64 * 128];   // 16 KB x2

    const int tid = threadIdx.x;
    const int bid = blockIdx.x;
    const int xcd = bid & 7;
    const int m0 = (bid >> 4) * 32;
    const int n0 = (xcd * 2 + ((bid >> 3) & 1)) * 64;
    const int lane = tid & 63, wid = tid >> 6;
    const int wm = wid >> 1, wn = wid & 1;

    f32x4 acc[2];
    const f32x4 fz = {0.f, 0.f, 0.f, 0.f};
    acc[0] = fz; acc[1] = fz;

    auto stage = [&](int t, int buf) {
#pragma unroll
        for (int i = 0; i < 2; i++) {
            int cpos = tid + i * 256;          // 0..511
            int m = cpos >> 4, p = cpos & 15;
            int g = p ^ (m & 7);
            int vk = t * 128 + g * 8;
            int acol = (vk < 512) ? vk : vk - 512;
            GLOAD_LDS16(&A2in[(size_t)(m0 + m) * 1024 + acol], &lA[buf][cpos * 8]);
        }
#pragma unroll
        for (int i = 0; i < 4; i++) {
            int cpos = tid + i * 256;          // 0..1023
            int n = cpos >> 4, p = cpos & 15;
            int g = p ^ (n & 7);
            GLOAD_LDS16(&B2[(size_t)(n0 + n) * 1536 + t * 128 + g * 8], &lB[buf][cpos * 8]);
        }
    };

    stage(0, 0);
    stage(1, 1);

    for (int t = 0; t < 12; t++) {
        int cur = t & 1;
        if (t < 11) asm volatile("s_waitcnt vmcnt(6)" ::: "memory");
        else        asm volatile("s_waitcnt vmcnt(0)" ::: "memory");
        __syncthreads();
        {
            int m = wm * 16 + (lane & 15);
#pragma unroll
            for (int kk = 0; kk < 4; kk++) {
                int g = kk * 4 + (lane >> 4);
                bf16x8 a0 = *(const bf16x8*)&lA[cur][m * 128 + ((g ^ (m & 7)) << 3)];
#pragma unroll
                for (int ni = 0; ni < 2; ni++) {
                    int n = wn * 32 + ni * 16 + (lane & 15);
                    bf16x8 bq = *(const bf16x8*)&lB[cur][n * 128 + ((g ^ (n & 7)) << 3)];
                    acc[ni] = __builtin_amdgcn_mfma_f32_16x16x32_bf16(a0, bq, acc[ni], 0, 0, 0);
                }
            }
        }
        __syncthreads();
        if (t + 2 < 12) stage(t + 2, cur);
    }

    // ---- epilogue 1: gates tile (32x64) -> LDS (bias + onehot) ----
    float* ltile = (float*)&lA[0][0];   // 8 KB = lA[0]
    const int r4 = (lane >> 4) * 4;
#pragma unroll
    for (int ni = 0; ni < 2; ni++) {
        int colg = n0 + wn * 32 + ni * 16 + (lane & 15);
        int jorig = ((colg & 3) << 8) + (colg >> 2);
        float bsum = b_ih[jorig] + b_hh[jorig];
        const float* wcol = &w_ih[(size_t)jorig * 294 + 256];
        int col_l = colg - n0;
#pragma unroll
        for (int r = 0; r < 4; r++) {
            int row_l = wm * 16 + r4 + r;
            int cl = text[(m0 + row_l) * NSTEP + step];
            ltile[row_l * 64 + col_l] = acc[ni][r] + bsum + wcol[cl];
        }
    }
    __syncthreads();

    // ---- epilogue 2: LSTM for 32 rows x 16 hh ----
    const int hh0 = n0 >> 2;
#pragma unroll
    for (int it = 0; it < 2; it++) {
        int idx = tid + it * 256;
        int row_l = idx >> 4, hl = idx & 15;
        int row = m0 + row_l;
        int hh = hh0 + hl;
        float gi = ltile[row_l * 64 + hl * 4 + 0];
        float gf = ltile[row_l * 64 + hl * 4 + 1];
        float gg = ltile[row_l * 64 + hl * 4 + 2];
        float go = ltile[row_l * 64 + hl * 4 + 3];
        float cv = c[(size_t)row * HD + hh];
        float cn = fast_sig(gf) * cv + fast_sig(gi) * fast_tanh(gg);
        float hn = fast_sig(go) * fast_tanh(cn);
        c[(size_t)row * HD + hh] = cn;
        h[(size_t)row * HD + hh] = hn;
        unsigned short hi_ = f2bf(hn);
        unsigned short lo_ = f2bf(hn - bf2f(hi_));
        A2out[(size_t)row * 1024 + 256 + hh] = hi_;
        A2out[(size_t)row * 1024 + 768 + hh] = lo_;
        size_t hr = ((size_t)step * NB + row) * 512;
        hseq2[hr + hh] = hi_;
        hseq2[hr + 256 + hh] = lo_;
    }
}

// ---------------------------------------------------------------------------
// attn_full: hp + scores + softmax + ctx + A2 ctx-parts.
// 256 blocks x 512 threads, 4 rows/block.  T14: Hb + encb register slices
// PREFETCHED at kernel entry (HBM latency hides under h-load + hp phase).
// ---------------------------------------------------------------------------
__global__ __launch_bounds__(512) void attn_full(
    const float* __restrict__ h,
    const ushort_t* __restrict__ w2hb, const float* __restrict__ b_h2h,
    const float* __restrict__ w_score,
    const ushort_t* __restrict__ encb, const ushort_t* __restrict__ Hb,
    ushort_t* __restrict__ A2)
{
    __shared__ float hsh[4][HD];          // 4 KB
    __shared__ float hpp[2][4][HD];       // 8 KB  (hp partials)
    __shared__ float hpsh[4][HD];         // 4 KB
    __shared__ float wssh[HD];            // 1 KB
    __shared__ float esh[4][TT];          // 0.5 KB
    __shared__ float psh[4][4][HD + 1];   // 16.1 KB

    const int tid = threadIdx.x;
    const int bid = blockIdx.x;
    const int b0 = (bid & 7) * 128 + (bid >> 3) * 4;

    // ---- T14 prefetch: scores slice (64 d of one (row,t)) ----
    us8 hbv[8];
    {
        int pr = tid >> 2, q = tid & 3;
        int row = pr >> 5, t = pr & 31;
        const ushort_t* hr = &Hb[((size_t)(b0 + row) * TT + t) * HD + q * 64];
#pragma unroll
        for (int jj = 0; jj < 8; jj++)
            hbv[jj] = *(const us8*)&hr[jj * 8];
    }
    // ---- T14 prefetch: ctx slice (8 t x 8 d of one row) ----
    us8 ebv[8];
    {
        int row = tid >> 7, rem = tid & 127;
        int g = rem >> 5, l = rem & 31;
        const ushort_t* er = &encb[((size_t)(b0 + row) * TT + g * 8) * DIN + l * 8];
#pragma unroll
        for (int tt = 0; tt < 8; tt++)
            ebv[tt] = *(const us8*)&er[(size_t)tt * DIN];
    }

    if (tid < 256) wssh[tid] = w_score[tid];
#pragma unroll
    for (int it = 0; it < 2; it++) {
        int idx = tid + it * 512;
        int row = idx >> 8, d = idx & 255;
        hsh[row][d] = h[(size_t)(b0 + row) * HD + d];
    }
    __syncthreads();

    // hp partials: 2 threads per j (half d-range each), 4 rows, 8 chains
    {
        int j = tid & 255, half = tid >> 8;
        const ushort_t* wr = &w2hb[(size_t)j * HD + half * 128];
        float a[4] = {0.f, 0.f, 0.f, 0.f};
        float b[4] = {0.f, 0.f, 0.f, 0.f};
#pragma unroll 2
        for (int d = 0; d < 128; d += 16) {
            us8 w0 = *(const us8*)&wr[d];
            us8 w1 = *(const us8*)&wr[d + 8];
#pragma unroll
            for (int k = 0; k < 8; k++) {
                float f0 = bf2f(w0[k]), f1 = bf2f(w1[k]);
                int dd = half * 128 + d + k;
#pragma unroll
                for (int r = 0; r < 4; r++) {
                    a[r] += f0 * hsh[r][dd];
                    b[r] += f1 * hsh[r][dd + 8];
                }
            }
        }
#pragma unroll
        for (int r = 0; r < 4; r++)
            hpp[half][r][j] = a[r] + b[r];
    }
    __syncthreads();
    // combine hp partials + bias
#pragma unroll
    for (int it = 0; it < 2; it++) {
        int idx = tid + it * 512;
        int r = idx >> 8, j = idx & 255;
        hpsh[r][j] = hpp[0][r][j] + hpp[1][r][j] + b_h2h[j];
    }
    __syncthreads();

    // scores from prefetched registers: 4 threads per (row,t), 64 d each
    {
        int pr = tid >> 2, q = tid & 3;
        int row = pr >> 5, t = pr & 31;
        int d0 = q * 64;
        const float* hp = &hpsh[row][d0];
        const float* wp = &wssh[d0];
        float e0 = 0.f, e1 = 0.f;
#pragma unroll
        for (int jj = 0; jj < 8; jj += 2) {
            us8 hv0 = hbv[jj];
            us8 hv1 = hbv[jj + 1];
#pragma unroll
            for (int k = 0; k < 8; k++) {
                e0 += wp[jj * 8 + k] * fast_tanh(bf2f(hv0[k]) + hp[jj * 8 + k]);
                e1 += wp[jj * 8 + 8 + k] * fast_tanh(bf2f(hv1[k]) + hp[jj * 8 + 8 + k]);
            }
        }
        float e = e0 + e1;
        e += __shfl_xor(e, 1);
        e += __shfl_xor(e, 2);
        if (q == 0) esh[row][t] = e;
    }
    __syncthreads();

    // softmax over 32 t, 4 rows on 32-lane groups (2 waves)
    if (tid < 128) {
        int row = tid >> 5, l = tid & 31;
        float v = esh[row][l];
        float m = v;
#pragma unroll
        for (int o = 16; o > 0; o >>= 1) m = fmaxf(m, __shfl_xor(m, o));
        float p = __expf(v - m);
        float ssum = p;
#pragma unroll
        for (int o = 16; o > 0; o >>= 1) ssum += __shfl_xor(ssum, o);
        esh[row][l] = p * __builtin_amdgcn_rcpf(ssum);
    }
    __syncthreads();

    // context from prefetched registers: 128 threads/row, 4 groups of 8 t
    {
        int row = tid >> 7, rem = tid & 127;
        int g = rem >> 5, l = rem & 31;
        float pp[8] = {0.f, 0.f, 0.f, 0.f, 0.f, 0.f, 0.f, 0.f};
#pragma unroll
        for (int tt = 0; tt < 8; tt++) {
            float a = esh[row][g * 8 + tt];
            us8 ev = ebv[tt];
#pragma unroll
            for (int k = 0; k < 8; k++)
                pp[k] += a * bf2f(ev[k]);
        }
#pragma unroll
        for (int k = 0; k < 8; k++)
            psh[row][g][l * 8 + k] = pp[k];
    }
    __syncthreads();
#pragma unroll
    for (int it = 0; it < 2; it++) {
        int idx = tid + it * 512;
        int row = idx >> 8, d = idx & 255;
        float a = psh[row][0][d] + psh[row][1][d] + psh[row][2][d] + psh[row][3][d];
        unsigned short hi_ = f2bf(a);
        A2[(size_t)(b0 + row) * 1024 + d] = hi_;
        A2[(size_t)(b0 + row) * 1024 + 512 + d] = f2bf(a - bf2f(hi_));
    }
}

// ---------------------------------------------------------------------------
// probs_mfma: probs = hseq2 @ w_genP.T  (split-bf16, virtual K=768)
// (verbatim, proven)
// ---------------------------------------------------------------------------
__global__ __launch_bounds__(256) void probs_mfma(
    const ushort_t* __restrict__ hseq2, const ushort_t* __restrict__ w_genP,
    const float* __restrict__ b_gen, float* __restrict__ probs)
{
    __shared__ ushort_t lA[2][64 * 128];
    __shared__ ushort_t lB[2][64 * 128];

    const int tid = threadIdx.x;
    const int lane = tid & 63, wid = tid >> 6;
    const int wm = wid >> 1, wn = wid & 1;
    const int m0 = blockIdx.x * 64;

    f32x4 acc[2][2];
    const f32x4 fz = {0.f, 0.f, 0.f, 0.f};
    acc[0][0] = fz; acc[0][1] = fz; acc[1][0] = fz; acc[1][1] = fz;

    auto stage = [&](int t, int buf) {
#pragma unroll
        for (int i = 0; i < 4; i++) {
            int cpos = tid + i * 256;
            int m = cpos >> 4, p = cpos & 15;
            int g = p ^ (m & 7);
            int vk = t * 128 + g * 8;
            int acol = (vk < 256) ? vk : vk - 256;
            GLOAD_LDS16(&hseq2[(size_t)(m0 + m) * 512 + acol], &lA[buf][cpos * 8]);
        }
#pragma unroll
        for (int i = 0; i < 4; i++) {
            int cpos = tid + i * 256;
            int n = cpos >> 4, p = cpos & 15;
            int g = p ^ (n & 7);
            GLOAD_LDS16(&w_genP[(size_t)n * 768 + t * 128 + g * 8], &lB[buf][cpos * 8]);
        }
    };

    stage(0, 0);
    stage(1, 1);

    for (int t = 0; t < 6; t++) {
        int cur = t & 1;
        if (t < 5) asm volatile("s_waitcnt vmcnt(8)" ::: "memory");
        else       asm volatile("s_waitcnt vmcnt(0)" ::: "memory");
        __syncthreads();
#pragma unroll
        for (int kk = 0; kk < 4; kk++) {
            int g = kk * 4 + (lane >> 4);
            bf16x8 af[2], bfr[2];
#pragma unroll
            for (int mi = 0; mi < 2; mi++) {
                int m = wm * 32 + mi * 16 + (lane & 15);
                af[mi] = *(const bf16x8*)&lA[cur][m * 128 + ((g ^ (m & 7)) << 3)];
            }
#pragma unroll
            for (int ni = 0; ni < 2; ni++) {
                int n = wn * 32 + ni * 16 + (lane & 15);
                bfr[ni] = *(const bf16x8*)&lB[cur][n * 128 + ((g ^ (n & 7)) << 3)];
            }
#pragma unroll
            for (int mi = 0; mi < 2; mi++)
#pragma unroll
                for (int ni = 0; ni < 2; ni++)
                    acc[mi][ni] = __builtin_amdgcn_mfma_f32_16x16x32_bf16(af[mi], bfr[ni], acc[mi][ni], 0, 0, 0);
        }
        __syncthreads();
        if (t + 2 < 6) stage(t + 2, cur);
    }

    const int r4 = (lane >> 4) * 4;
    const int s = blockIdx.x >> 4;
    const int b0 = (blockIdx.x & 15) * 64;
#pragma unroll
    for (int ni = 0; ni < 2; ni++) {
        int col = wn * 32 + ni * 16 + (lane & 15);
        if (col < NC) {
            float bb = b_gen[col];
#pragma unroll
            for (int mi = 0; mi < 2; mi++)
#pragma unroll
                for (int r = 0; r < 4; r++) {
                    int b = b0 + wm * 32 + mi * 16 + r4 + r;
                    probs[((size_t)b * NSTEP + s) * NC + col] = acc[mi][ni][r] + bb;
                }
        }
    }
}

// ---------------------------------------------------------------------------
extern "C" void kernel_launch(void* const* d_in, const int* in_sizes, int n_in,
                              void* d_out, int out_size, void* d_ws, size_t ws_size,
                              hipStream_t stream)
{
    const float* enc     = (const float*)d_in[0];
    const int*   text    = (const int*)d_in[1];
    const float* w_i2h   = (const float*)d_in[4];
    const float* w_h2h   = (const float*)d_in[5];
    const float* b_h2h   = (const float*)d_in[6];
    const float* w_score = (const float*)d_in[7];
    const float* w_ih    = (const float*)d_in[8];
    const float* w_hh    = (const float*)d_in[9];
    const float* b_ih    = (const float*)d_in[10];
    const float* b_hh    = (const float*)d_in[11];
    const float* w_gen   = (const float*)d_in[12];
    const float* b_gen   = (const float*)d_in[13];
    float* out = (float*)d_out;

    const size_t MB = 1024 * 1024;
    char* ws = (char*)d_ws;
    ushort_t* Hb     = (ushort_t*)ws;                          // 16 MB  [0,16)
    ushort_t* B2g    = (ushort_t*)(ws + 16 * MB);              // 3 MB   [16,19)
    ushort_t* B2i    = (ushort_t*)(ws + 19 * MB);              // 384 KB
    ushort_t* w2hb   = (ushort_t*)(ws + 19 * MB + 512 * 1024); // 128 KB
    ushort_t* w_genP = (ushort_t*)(ws + 19 * MB + 768 * 1024); // 96 KB
    float*    cbuf   = (float*)(ws + 20 * MB);                 // 1 MB   [20,21)
    float*    hbuf   = (float*)(ws + 21 * MB);                 // 1 MB   [21,22)
    ushort_t* A2     = (ushort_t*)(ws + 22 * MB);              // 2 MB   [22,24)
    ushort_t* encA2  = (ushort_t*)(ws + 27 * MB);              // 32 MB  [27,59)
    ushort_t* hseq2  = (ushort_t*)(ws + 27 * MB);              // 26 MB, overlays encA2
    ushort_t* encb   = (ushort_t*)(ws + 59 * MB);              // 16 MB  [59,75)
    float*    zbase  = cbuf;                                   // zero {c,h,A2} = 4 MB

    prep_all<<<3904, 256, 0, stream>>>(w_ih, w_hh, w_i2h, w_h2h, enc, w_gen,
                                       B2g, B2i, w2hb, encA2, encb, w_genP, zbase);
    hproj_pipe<<<dim3(512, 4), 256, 0, stream>>>(encA2, B2i, Hb);

    for (int s = 0; s < NSTEP; s++) {
        attn_full<<<256, 512, 0, stream>>>(hbuf, w2hb, b_h2h, w_score,
                                           encb, Hb, A2);
        gates_lstm<<<512, 256, 0, stream>>>(A2, B2g, b_ih, b_hh, w_ih, text,
                                            cbuf, hbuf, A2, hseq2, s);
    }
    probs_mfma<<<416, 256, 0, stream>>>(hseq2, w_genP, b_gen, out);
}

// Round 21
// 815.456 us; speedup vs baseline: 1.0344x; 1.0344x over previous
//
#include <hip/hip_runtime.h>

#define NB 1024   // batch
#define TT 32     // encoder length
#define DIN 256   // input dim
#define HD 256    // hidden dim
#define NC 38     // classes
#define NSTEP 26  // decode steps

typedef unsigned short ushort_t;
typedef __attribute__((ext_vector_type(8))) short bf16x8;
typedef __attribute__((ext_vector_type(8))) unsigned short us8;
typedef __attribute__((ext_vector_type(4))) float f32x4;

#define GLOAD_LDS16(g, l) \
  __builtin_amdgcn_global_load_lds((const __attribute__((address_space(1))) unsigned int*)(g), \
                                   (__attribute__((address_space(3))) unsigned int*)(l), 16, 0, 0)

__device__ __forceinline__ unsigned short f2bf(float x) {
    union { float f; unsigned u; } v; v.f = x;
    unsigned r = v.u + 0x7fff + ((v.u >> 16) & 1);   // RNE
    return (unsigned short)(r >> 16);
}
__device__ __forceinline__ float bf2f(unsigned short h) {
    union { unsigned u; float f; } v; v.u = ((unsigned)h) << 16;
    return v.f;
}
__device__ __forceinline__ float fast_tanh(float x) {
    float xc = fminf(fmaxf(x, -15.f), 15.f);
    float z = __expf(2.f * xc);
    return (z - 1.f) * __builtin_amdgcn_rcpf(z + 1.f);
}
__device__ __forceinline__ float fast_sig(float x) {
    return __builtin_amdgcn_rcpf(1.f + __expf(-x));
}

// ---------------------------------------------------------------------------
// prep_all: 3904 blocks.  (proven)
// ---------------------------------------------------------------------------
__global__ __launch_bounds__(256) void prep_all(
    const float* __restrict__ w_ih, const float* __restrict__ w_hh,
    const float* __restrict__ w_i2h, const float* __restrict__ w_h2h,
    const float* __restrict__ enc, const float* __restrict__ w_gen,
    ushort_t* __restrict__ B2g, ushort_t* __restrict__ B2i,
    ushort_t* __restrict__ w2hb, ushort_t* __restrict__ encA2,
    ushort_t* __restrict__ encb, ushort_t* __restrict__ w_genP,
    float* __restrict__ zbase)
{
    const int bid = blockIdx.x, tid = threadIdx.x;
    if (bid < 1024) {
        int j = bid;
        int jorig = ((j & 3) << 8) + (j >> 2);   // gate-interleaved cols
        for (int k = tid; k < 512; k += 256) {
            float x = (k < 256) ? w_ih[(size_t)jorig * 294 + k]
                                : w_hh[(size_t)jorig * 256 + (k - 256)];
            unsigned short hi = f2bf(x);
            unsigned short lo = f2bf(x - bf2f(hi));
            size_t r = (size_t)j * 1536;
            B2g[r + k] = hi; B2g[r + 512 + k] = lo; B2g[r + 1024 + k] = hi;
        }
    } else if (bid < 1280) {
        int n = bid - 1024;
        float x = w_i2h[(size_t)n * 256 + tid];
        unsigned short hi = f2bf(x);
        unsigned short lo = f2bf(x - bf2f(hi));
        size_t r = (size_t)n * 768;
        B2i[r + tid] = hi; B2i[r + 256 + tid] = lo; B2i[r + 512 + tid] = hi;
    } else if (bid < 1536) {
        int j = bid - 1280;
        w2hb[(size_t)j * 256 + tid] = f2bf(w_h2h[(size_t)j * 256 + tid]);
    } else if (bid < 3584) {
        int base = (bid - 1536) * 16;
#pragma unroll
        for (int rr = 0; rr < 16; rr++) {
            size_t row = base + rr;
            float x = enc[row * 256 + tid];
            unsigned short hi = f2bf(x);
            unsigned short lo = f2bf(x - bf2f(hi));
            encA2[row * 512 + tid] = hi;
            encA2[row * 512 + 256 + tid] = lo;
            encb[row * 256 + tid] = hi;
        }
    } else if (bid < 3648) {
        int j = bid - 3584;
        float x = (j < NC) ? w_gen[(size_t)j * 256 + tid] : 0.f;
        unsigned short hi = f2bf(x);
        unsigned short lo = f2bf(x - bf2f(hi));
        size_t r = (size_t)j * 768;
        w_genP[r + tid] = hi; w_genP[r + 256 + tid] = lo; w_genP[r + 512 + tid] = hi;
    } else {
        float* z = zbase + (size_t)(bid - 3648) * 4096;
        const float4 f4z = make_float4(0.f, 0.f, 0.f, 0.f);
#pragma unroll
        for (int k = 0; k < 4; k++)
            *(float4*)&z[(tid + k * 256) * 4] = f4z;
    }
}

// ---------------------------------------------------------------------------
// hproj_pipe: Hb[m][n] = bf16( sum_k enc[m][k]*w_i2h[n][k] )   (proven)
// ---------------------------------------------------------------------------
__global__ __launch_bounds__(256) void hproj_pipe(
    const ushort_t* __restrict__ encA2, const ushort_t* __restrict__ B2i,
    ushort_t* __restrict__ Hb)
{
    __shared__ ushort_t lA[2][64 * 128];
    __shared__ ushort_t lB[2][64 * 128];

    const int tid = threadIdx.x;
    const int lane = tid & 63, wid = tid >> 6;
    const int wm = wid >> 1, wn = wid & 1;
    const int m0 = blockIdx.x * 64, n0 = blockIdx.y * 64;

    f32x4 acc[2][2];
    const f32x4 fz = {0.f, 0.f, 0.f, 0.f};
    acc[0][0] = fz; acc[0][1] = fz; acc[1][0] = fz; acc[1][1] = fz;

    auto stage = [&](int t, int buf) {
#pragma unroll
        for (int i = 0; i < 4; i++) {
            int cpos = tid + i * 256;
            int m = cpos >> 4, p = cpos & 15;
            int g = p ^ (m & 7);
            int vk = t * 128 + g * 8;
            int acol = (vk < 256) ? vk : vk - 256;
            GLOAD_LDS16(&encA2[(size_t)(m0 + m) * 512 + acol], &lA[buf][cpos * 8]);
        }
#pragma unroll
        for (int i = 0; i < 4; i++) {
            int cpos = tid + i * 256;
            int n = cpos >> 4, p = cpos & 15;
            int g = p ^ (n & 7);
            GLOAD_LDS16(&B2i[(size_t)(n0 + n) * 768 + t * 128 + g * 8], &lB[buf][cpos * 8]);
        }
    };

    stage(0, 0);
    stage(1, 1);

    for (int t = 0; t < 6; t++) {
        int cur = t & 1;
        if (t < 5) asm volatile("s_waitcnt vmcnt(8)" ::: "memory");
        else       asm volatile("s_waitcnt vmcnt(0)" ::: "memory");
        __syncthreads();
#pragma unroll
        for (int kk = 0; kk < 4; kk++) {
            int g = kk * 4 + (lane >> 4);
            bf16x8 af[2], bfr[2];
#pragma unroll
            for (int mi = 0; mi < 2; mi++) {
                int m = wm * 32 + mi * 16 + (lane & 15);
                af[mi] = *(const bf16x8*)&lA[cur][m * 128 + ((g ^ (m & 7)) << 3)];
            }
#pragma unroll
            for (int ni = 0; ni < 2; ni++) {
                int n = wn * 32 + ni * 16 + (lane & 15);
                bfr[ni] = *(const bf16x8*)&lB[cur][n * 128 + ((g ^ (n & 7)) << 3)];
            }
#pragma unroll
            for (int mi = 0; mi < 2; mi++)
#pragma unroll
                for (int ni = 0; ni < 2; ni++)
                    acc[mi][ni] = __builtin_amdgcn_mfma_f32_16x16x32_bf16(af[mi], bfr[ni], acc[mi][ni], 0, 0, 0);
        }
        __syncthreads();
        if (t + 2 < 6) stage(t + 2, cur);
    }

    const int r4 = (lane >> 4) * 4;
#pragma unroll
    for (int mi = 0; mi < 2; mi++)
#pragma unroll
        for (int r = 0; r < 4; r++) {
            size_t row = m0 + wm * 32 + mi * 16 + r4 + r;
#pragma unroll
            for (int ni = 0; ni < 2; ni++) {
                int col = n0 + wn * 32 + ni * 16 + (lane & 15);
                Hb[row * 256 + col] = f2bf(acc[mi][ni][r]);
            }
        }
}

// ---------------------------------------------------------------------------
// gates_lstm: gates GEMM + fused LSTM epilogue.  BM=32, 512 blocks (2/CU).
// (proven round 18/19)
// ---------------------------------------------------------------------------
__global__ __launch_bounds__(256) void gates_lstm(
    const ushort_t* __restrict__ A2in, const ushort_t* __restrict__ B2,
    const float* __restrict__ b_ih, const float* __restrict__ b_hh,
    const float* __restrict__ w_ih, const int* __restrict__ text,
    float* __restrict__ c, float* __restrict__ h,
    ushort_t* __restrict__ A2out, ushort_t* __restrict__ hseq2,
    int step)
{
    __shared__ ushort_t lA[2][32 * 128];   // 8 KB x2
    __shared__ ushort_t lB[2][64 * 128];   // 16 KB x2

    const int tid = threadIdx.x;
    const int bid = blockIdx.x;
    const int xcd = bid & 7;
    const int m0 = (bid >> 4) * 32;
    const int n0 = (xcd * 2 + ((bid >> 3) & 1)) * 64;
    const int lane = tid & 63, wid = tid >> 6;
    const int wm = wid >> 1, wn = wid & 1;

    f32x4 acc[2];
    const f32x4 fz = {0.f, 0.f, 0.f, 0.f};
    acc[0] = fz; acc[1] = fz;

    auto stage = [&](int t, int buf) {
#pragma unroll
        for (int i = 0; i < 2; i++) {
            int cpos = tid + i * 256;          // 0..511
            int m = cpos >> 4, p = cpos & 15;
            int g = p ^ (m & 7);
            int vk = t * 128 + g * 8;
            int acol = (vk < 512) ? vk : vk - 512;
            GLOAD_LDS16(&A2in[(size_t)(m0 + m) * 1024 + acol], &lA[buf][cpos * 8]);
        }
#pragma unroll
        for (int i = 0; i < 4; i++) {
            int cpos = tid + i * 256;          // 0..1023
            int n = cpos >> 4, p = cpos & 15;
            int g = p ^ (n & 7);
            GLOAD_LDS16(&B2[(size_t)(n0 + n) * 1536 + t * 128 + g * 8], &lB[buf][cpos * 8]);
        }
    };

    stage(0, 0);
    stage(1, 1);

    for (int t = 0; t < 12; t++) {
        int cur = t & 1;
        if (t < 11) asm volatile("s_waitcnt vmcnt(6)" ::: "memory");
        else        asm volatile("s_waitcnt vmcnt(0)" ::: "memory");
        __syncthreads();
        {
            int m = wm * 16 + (lane & 15);
#pragma unroll
            for (int kk = 0; kk < 4; kk++) {
                int g = kk * 4 + (lane >> 4);
                bf16x8 a0 = *(const bf16x8*)&lA[cur][m * 128 + ((g ^ (m & 7)) << 3)];
#pragma unroll
                for (int ni = 0; ni < 2; ni++) {
                    int n = wn * 32 + ni * 16 + (lane & 15);
                    bf16x8 bq = *(const bf16x8*)&lB[cur][n * 128 + ((g ^ (n & 7)) << 3)];
                    acc[ni] = __builtin_amdgcn_mfma_f32_16x16x32_bf16(a0, bq, acc[ni], 0, 0, 0);
                }
            }
        }
        __syncthreads();
        if (t + 2 < 12) stage(t + 2, cur);
    }

    // ---- epilogue 1: gates tile (32x64) -> LDS (bias + onehot) ----
    float* ltile = (float*)&lA[0][0];   // 8 KB = lA[0]
    const int r4 = (lane >> 4) * 4;
#pragma unroll
    for (int ni = 0; ni < 2; ni++) {
        int colg = n0 + wn * 32 + ni * 16 + (lane & 15);
        int jorig = ((colg & 3) << 8) + (colg >> 2);
        float bsum = b_ih[jorig] + b_hh[jorig];
        const float* wcol = &w_ih[(size_t)jorig * 294 + 256];
        int col_l = colg - n0;
#pragma unroll
        for (int r = 0; r < 4; r++) {
            int row_l = wm * 16 + r4 + r;
            int cl = text[(m0 + row_l) * NSTEP + step];
            ltile[row_l * 64 + col_l] = acc[ni][r] + bsum + wcol[cl];
        }
    }
    __syncthreads();

    // ---- epilogue 2: LSTM for 32 rows x 16 hh ----
    const int hh0 = n0 >> 2;
#pragma unroll
    for (int it = 0; it < 2; it++) {
        int idx = tid + it * 256;
        int row_l = idx >> 4, hl = idx & 15;
        int row = m0 + row_l;
        int hh = hh0 + hl;
        float gi = ltile[row_l * 64 + hl * 4 + 0];
        float gf = ltile[row_l * 64 + hl * 4 + 1];
        float gg = ltile[row_l * 64 + hl * 4 + 2];
        float go = ltile[row_l * 64 + hl * 4 + 3];
        float cv = c[(size_t)row * HD + hh];
        float cn = fast_sig(gf) * cv + fast_sig(gi) * fast_tanh(gg);
        float hn = fast_sig(go) * fast_tanh(cn);
        c[(size_t)row * HD + hh] = cn;
        h[(size_t)row * HD + hh] = hn;
        unsigned short hi_ = f2bf(hn);
        unsigned short lo_ = f2bf(hn - bf2f(hi_));
        A2out[(size_t)row * 1024 + 256 + hh] = hi_;
        A2out[(size_t)row * 1024 + 768 + hh] = lo_;
        size_t hr = ((size_t)step * NB + row) * 512;
        hseq2[hr + hh] = hi_;
        hseq2[hr + 256 + hh] = lo_;
    }
}

// ---------------------------------------------------------------------------
// attn_full: hp + scores + softmax + ctx + A2 ctx-parts.
// 256 blocks x 512 threads, 4 rows/block.  (round-19 champion, verbatim)
// ---------------------------------------------------------------------------
__global__ __launch_bounds__(512) void attn_full(
    const float* __restrict__ h,
    const ushort_t* __restrict__ w2hb, const float* __restrict__ b_h2h,
    const float* __restrict__ w_score,
    const ushort_t* __restrict__ encb, const ushort_t* __restrict__ Hb,
    ushort_t* __restrict__ A2)
{
    __shared__ float hsh[4][HD];          // 4 KB
    __shared__ float hpp[2][4][HD];       // 8 KB  (hp partials)
    __shared__ float hpsh[4][HD];         // 4 KB
    __shared__ float wssh[HD];            // 1 KB
    __shared__ float esh[4][TT];          // 0.5 KB
    __shared__ float psh[4][4][HD + 1];   // 16.1 KB

    const int tid = threadIdx.x;
    const int bid = blockIdx.x;
    const int b0 = (bid & 7) * 128 + (bid >> 3) * 4;

    if (tid < 256) wssh[tid] = w_score[tid];
#pragma unroll
    for (int it = 0; it < 2; it++) {
        int idx = tid + it * 512;
        int row = idx >> 8, d = idx & 255;
        hsh[row][d] = h[(size_t)(b0 + row) * HD + d];
    }
    __syncthreads();

    // hp partials: 2 threads per j (half d-range each), 4 rows, 8 chains
    {
        int j = tid & 255, half = tid >> 8;
        const ushort_t* wr = &w2hb[(size_t)j * HD + half * 128];
        float a[4] = {0.f, 0.f, 0.f, 0.f};
        float b[4] = {0.f, 0.f, 0.f, 0.f};
#pragma unroll 2
        for (int d = 0; d < 128; d += 16) {
            us8 w0 = *(const us8*)&wr[d];
            us8 w1 = *(const us8*)&wr[d + 8];
#pragma unroll
            for (int k = 0; k < 8; k++) {
                float f0 = bf2f(w0[k]), f1 = bf2f(w1[k]);
                int dd = half * 128 + d + k;
#pragma unroll
                for (int r = 0; r < 4; r++) {
                    a[r] += f0 * hsh[r][dd];
                    b[r] += f1 * hsh[r][dd + 8];
                }
            }
        }
#pragma unroll
        for (int r = 0; r < 4; r++)
            hpp[half][r][j] = a[r] + b[r];
    }
    __syncthreads();
    // combine hp partials + bias
#pragma unroll
    for (int it = 0; it < 2; it++) {
        int idx = tid + it * 512;
        int r = idx >> 8, j = idx & 255;
        hpsh[r][j] = hpp[0][r][j] + hpp[1][r][j] + b_h2h[j];
    }
    __syncthreads();

    // scores: 4 threads per (row,t), 64 d each; 2 partial e chains
    {
        int pr = tid >> 2, q = tid & 3;
        int row = pr >> 5, t = pr & 31;
        int d0 = q * 64;
        const ushort_t* hr = &Hb[((size_t)(b0 + row) * TT + t) * HD + d0];
        const float* hp = &hpsh[row][d0];
        const float* wp = &wssh[d0];
        float e0 = 0.f, e1 = 0.f;
#pragma unroll
        for (int jj = 0; jj < 8; jj += 2) {
            us8 hv0 = *(const us8*)&hr[jj * 8];
            us8 hv1 = *(const us8*)&hr[jj * 8 + 8];
#pragma unroll
            for (int k = 0; k < 8; k++) {
                e0 += wp[jj * 8 + k] * fast_tanh(bf2f(hv0[k]) + hp[jj * 8 + k]);
                e1 += wp[jj * 8 + 8 + k] * fast_tanh(bf2f(hv1[k]) + hp[jj * 8 + 8 + k]);
            }
        }
        float e = e0 + e1;
        e += __shfl_xor(e, 1);
        e += __shfl_xor(e, 2);
        if (q == 0) esh[row][t] = e;
    }
    __syncthreads();

    // softmax over 32 t, 4 rows on 32-lane groups (2 waves)
    if (tid < 128) {
        int row = tid >> 5, l = tid & 31;
        float v = esh[row][l];
        float m = v;
#pragma unroll
        for (int o = 16; o > 0; o >>= 1) m = fmaxf(m, __shfl_xor(m, o));
        float p = __expf(v - m);
        float ssum = p;
#pragma unroll
        for (int o = 16; o > 0; o >>= 1) ssum += __shfl_xor(ssum, o);
        esh[row][l] = p * __builtin_amdgcn_rcpf(ssum);
    }
    __syncthreads();

    // context: 128 threads/row, 4 groups of 8 t, 8 d per thread
    {
        int row = tid >> 7, rem = tid & 127;
        int g = rem >> 5, l = rem & 31;
        float pp[8] = {0.f, 0.f, 0.f, 0.f, 0.f, 0.f, 0.f, 0.f};
#pragma unroll
        for (int tt = 0; tt < 8; tt++) {
            int t = g * 8 + tt;
            float a = esh[row][t];
            us8 ev = *(const us8*)&encb[((size_t)(b0 + row) * TT + t) * DIN + l * 8];
#pragma unroll
            for (int k = 0; k < 8; k++)
                pp[k] += a * bf2f(ev[k]);
        }
#pragma unroll
        for (int k = 0; k < 8; k++)
            psh[row][g][l * 8 + k] = pp[k];
    }
    __syncthreads();
#pragma unroll
    for (int it = 0; it < 2; it++) {
        int idx = tid + it * 512;
        int row = idx >> 8, d = idx & 255;
        float a = psh[row][0][d] + psh[row][1][d] + psh[row][2][d] + psh[row][3][d];
        unsigned short hi_ = f2bf(a);
        A2[(size_t)(b0 + row) * 1024 + d] = hi_;
        A2[(size_t)(b0 + row) * 1024 + 512 + d] = f2bf(a - bf2f(hi_));
    }
}

// ---------------------------------------------------------------------------
// probs_mfma: probs = hseq2 @ w_genP.T  (split-bf16, virtual K=768)
// (proven)
// ---------------------------------------------------------------------------
__global__ __launch_bounds__(256) void probs_mfma(
    const ushort_t* __restrict__ hseq2, const ushort_t* __restrict__ w_genP,
    const float* __restrict__ b_gen, float* __restrict__ probs)
{
    __shared__ ushort_t lA[2][64 * 128];
    __shared__ ushort_t lB[2][64 * 128];

    const int tid = threadIdx.x;
    const int lane = tid & 63, wid = tid >> 6;
    const int wm = wid >> 1, wn = wid & 1;
    const int m0 = blockIdx.x * 64;

    f32x4 acc[2][2];
    const f32x4 fz = {0.f, 0.f, 0.f, 0.f};
    acc[0][0] = fz; acc[0][1] = fz; acc[1][0] = fz; acc[1][1] = fz;

    auto stage = [&](int t, int buf) {
#pragma unroll
        for (int i = 0; i < 4; i++) {
            int cpos = tid + i * 256;
            int m = cpos >> 4, p = cpos & 15;
            int g = p ^ (m & 7);
            int vk = t * 128 + g * 8;
            int acol = (vk < 256) ? vk : vk - 256;
            GLOAD_LDS16(&hseq2[(size_t)(m0 + m) * 512 + acol], &lA[buf][cpos * 8]);
        }
#pragma unroll
        for (int i = 0; i < 4; i++) {
            int cpos = tid + i * 256;
            int n = cpos >> 4, p = cpos & 15;
            int g = p ^ (n & 7);
            GLOAD_LDS16(&w_genP[(size_t)n * 768 + t * 128 + g * 8], &lB[buf][cpos * 8]);
        }
    };

    stage(0, 0);
    stage(1, 1);

    for (int t = 0; t < 6; t++) {
        int cur = t & 1;
        if (t < 5) asm volatile("s_waitcnt vmcnt(8)" ::: "memory");
        else       asm volatile("s_waitcnt vmcnt(0)" ::: "memory");
        __syncthreads();
#pragma unroll
        for (int kk = 0; kk < 4; kk++) {
            int g = kk * 4 + (lane >> 4);
            bf16x8 af[2], bfr[2];
#pragma unroll
            for (int mi = 0; mi < 2; mi++) {
                int m = wm * 32 + mi * 16 + (lane & 15);
                af[mi] = *(const bf16x8*)&lA[cur][m * 128 + ((g ^ (m & 7)) << 3)];
            }
#pragma unroll
            for (int ni = 0; ni < 2; ni++) {
                int n = wn * 32 + ni * 16 + (lane & 15);
                bfr[ni] = *(const bf16x8*)&lB[cur][n * 128 + ((g ^ (n & 7)) << 3)];
            }
#pragma unroll
            for (int mi = 0; mi < 2; mi++)
#pragma unroll
                for (int ni = 0; ni < 2; ni++)
                    acc[mi][ni] = __builtin_amdgcn_mfma_f32_16x16x32_bf16(af[mi], bfr[ni], acc[mi][ni], 0, 0, 0);
        }
        __syncthreads();
        if (t + 2 < 6) stage(t + 2, cur);
    }

    const int r4 = (lane >> 4) * 4;
    const int s = blockIdx.x >> 4;
    const int b0 = (blockIdx.x & 15) * 64;
#pragma unroll
    for (int ni = 0; ni < 2; ni++) {
        int col = wn * 32 + ni * 16 + (lane & 15);
        if (col < NC) {
            float bb = b_gen[col];
#pragma unroll
            for (int mi = 0; mi < 2; mi++)
#pragma unroll
                for (int r = 0; r < 4; r++) {
                    int b = b0 + wm * 32 + mi * 16 + r4 + r;
                    probs[((size_t)b * NSTEP + s) * NC + col] = acc[mi][ni][r] + bb;
                }
        }
    }
}

// ---------------------------------------------------------------------------
extern "C" void kernel_launch(void* const* d_in, const int* in_sizes, int n_in,
                              void* d_out, int out_size, void* d_ws, size_t ws_size,
                              hipStream_t stream)
{
    const float* enc     = (const float*)d_in[0];
    const int*   text    = (const int*)d_in[1];
    const float* w_i2h   = (const float*)d_in[4];
    const float* w_h2h   = (const float*)d_in[5];
    const float* b_h2h   = (const float*)d_in[6];
    const float* w_score = (const float*)d_in[7];
    const float* w_ih    = (const float*)d_in[8];
    const float* w_hh    = (const float*)d_in[9];
    const float* b_ih    = (const float*)d_in[10];
    const float* b_hh    = (const float*)d_in[11];
    const float* w_gen   = (const float*)d_in[12];
    const float* b_gen   = (const float*)d_in[13];
    float* out = (float*)d_out;

    const size_t MB = 1024 * 1024;
    char* ws = (char*)d_ws;
    ushort_t* Hb     = (ushort_t*)ws;                          // 16 MB  [0,16)
    ushort_t* B2g    = (ushort_t*)(ws + 16 * MB);              // 3 MB   [16,19)
    ushort_t* B2i    = (ushort_t*)(ws + 19 * MB);              // 384 KB
    ushort_t* w2hb   = (ushort_t*)(ws + 19 * MB + 512 * 1024); // 128 KB
    ushort_t* w_genP = (ushort_t*)(ws + 19 * MB + 768 * 1024); // 96 KB
    float*    cbuf   = (float*)(ws + 20 * MB);                 // 1 MB   [20,21)
    float*    hbuf   = (float*)(ws + 21 * MB);                 // 1 MB   [21,22)
    ushort_t* A2     = (ushort_t*)(ws + 22 * MB);              // 2 MB   [22,24)
    ushort_t* encA2  = (ushort_t*)(ws + 27 * MB);              // 32 MB  [27,59)
    ushort_t* hseq2  = (ushort_t*)(ws + 27 * MB);              // 26 MB, overlays encA2
    ushort_t* encb   = (ushort_t*)(ws + 59 * MB);              // 16 MB  [59,75)
    float*    zbase  = cbuf;                                   // zero {c,h,A2} = 4 MB

    prep_all<<<3904, 256, 0, stream>>>(w_ih, w_hh, w_i2h, w_h2h, enc, w_gen,
                                       B2g, B2i, w2hb, encA2, encb, w_genP, zbase);
    hproj_pipe<<<dim3(512, 4), 256, 0, stream>>>(encA2, B2i, Hb);

    for (int s = 0; s < NSTEP; s++) {
        attn_full<<<256, 512, 0, stream>>>(hbuf, w2hb, b_h2h, w_score,
                                           encb, Hb, A2);
        gates_lstm<<<512, 256, 0, stream>>>(A2, B2g, b_ih, b_hh, w_ih, text,
                                            cbuf, hbuf, A2, hseq2, s);
    }
    probs_mfma<<<416, 256, 0, stream>>>(hseq2, w_genP, b_gen, out);
}